// Round 4
// baseline (498.107 us; speedup 1.0000x reference)
//
#include <hip/hip_runtime.h>
#include <hip/hip_fp16.h>

#define NNODES 50000
#define NEDGES 800000
#define NHEADS 4
#define HID 64
#define NEG_SLOPE 0.2f
#define NTOT (NEDGES + NNODES)
#define NPAD (NTOT + 8)

// ---------------- graph prep ----------------

__global__ void prep_init(int* deg, int* cursor) {
    int i = blockIdx.x * blockDim.x + threadIdx.x;
    if (i < NNODES) { deg[i] = 1; cursor[i] = 0; }  // deg starts at 1: self-loop
}

__global__ void hist_kernel(const int* __restrict__ dsts, int* __restrict__ deg) {
    int e = blockIdx.x * blockDim.x + threadIdx.x;
    if (e < NEDGES) atomicAdd(&deg[dsts[e]], 1);
}

// hierarchical exclusive scan: A (per-block), B (block totals), C (add offsets)
__global__ void scanA(const int* __restrict__ deg, int* __restrict__ rowstart,
                      int* __restrict__ partials) {
    int b = blockIdx.x, t = threadIdx.x, lane = t & 63, wid = t >> 6;
    int i = b * 256 + t;
    int v = (i < NNODES) ? deg[i] : 0;
    int incl = v;
#pragma unroll
    for (int off = 1; off < 64; off <<= 1) {
        int u = __shfl_up(incl, off, 64);
        if (lane >= off) incl += u;
    }
    __shared__ int ws[4];
    if (lane == 63) ws[wid] = incl;
    __syncthreads();
    int w0 = ws[0], w1 = ws[1], w2 = ws[2], w3 = ws[3];
    int woff = (wid > 0 ? w0 : 0) + (wid > 1 ? w1 : 0) + (wid > 2 ? w2 : 0);
    if (i < NNODES) rowstart[i] = woff + (incl - v);
    if (t == 0) partials[b] = w0 + w1 + w2 + w3;
}

__global__ void scanB(const int* __restrict__ partials, int* __restrict__ blockoff,
                      int* __restrict__ rowstart, int nb) {
    int t = threadIdx.x, lane = t & 63, wid = t >> 6;
    int v = (t < nb) ? partials[t] : 0;
    int incl = v;
#pragma unroll
    for (int off = 1; off < 64; off <<= 1) {
        int u = __shfl_up(incl, off, 64);
        if (lane >= off) incl += u;
    }
    __shared__ int ws[4];
    if (lane == 63) ws[wid] = incl;
    __syncthreads();
    int w0 = ws[0], w1 = ws[1], w2 = ws[2];
    int woff = (wid > 0 ? w0 : 0) + (wid > 1 ? w1 : 0) + (wid > 2 ? w2 : 0);
    if (t < nb) blockoff[t] = woff + (incl - v);
    if (t == 0) rowstart[NNODES] = NTOT;
}

__global__ void scanC(int* __restrict__ rowstart, const int* __restrict__ blockoff) {
    int b = blockIdx.x, t = threadIdx.x;
    int i = b * 256 + t;
    if (i < NNODES) rowstart[i] += blockoff[b];
}

// also writes dst_sorted so edge weights can be computed edge-parallel later
__global__ void scatter_kernel(const int* __restrict__ srcs, const int* __restrict__ dsts,
                               const int* __restrict__ rowstart, int* __restrict__ cursor,
                               int* __restrict__ srclist, int* __restrict__ dst_sorted) {
    int e = blockIdx.x * blockDim.x + threadIdx.x;
    if (e < NEDGES) {
        int s = srcs[e], d = dsts[e];
        int pos = atomicAdd(&cursor[d], 1);
        int at = rowstart[d] + pos;
        srclist[at] = s;
        dst_sorted[at] = d;
    } else if (e < NTOT) {
        int d = e - NEDGES;
        int pos = atomicAdd(&cursor[d], 1);
        int at = rowstart[d] + pos;
        srclist[at] = d;  // self-loop
        dst_sorted[at] = d;
    }
}

__global__ void w2_convert(const float* __restrict__ W2, __half* __restrict__ W2h) {
    int i = blockIdx.x * blockDim.x + threadIdx.x;
    if (i < 256 * 64) W2h[i] = __float2half(W2[i]);
}

// ---------------- layer 1 ----------------

// one block (256 thr) per node: h1 = x @ W1, stored fp16 in XCD-sharded layout
// h1s[shard][node][32 halves] (64 B rows), shard = head*2 + (dim-half).
// attention dots stored AoS: asrc4[node] = float4 over heads.
__global__ void layer1_proj(const float* __restrict__ x, const float* __restrict__ W1,
                            const float* __restrict__ att_src, const float* __restrict__ att_dst,
                            __half* __restrict__ h1s, float* __restrict__ asrc4,
                            float* __restrict__ adst4) {
    int nid = blockIdx.x;
    int t = threadIdx.x;
    __shared__ float xr[16];
    if (t < 15) xr[t] = x[nid * 15 + t];
    __syncthreads();
    float acc = 0.f;
#pragma unroll
    for (int k = 0; k < 15; ++k) acc += xr[k] * W1[k * 256 + t];
    int h = t >> 6, hd = t & 63;
    int shard = h * 2 + (hd >> 5);
    h1s[((size_t)shard * NNODES + nid) * 32 + (hd & 31)] = __float2half(acc);
    float ps = acc * att_src[h * 64 + hd];
    float pd = acc * att_dst[h * 64 + hd];
#pragma unroll
    for (int off = 32; off; off >>= 1) {
        ps += __shfl_down(ps, off, 64);
        pd += __shfl_down(pd, off, 64);
    }
    if (hd == 0) { asrc4[nid * 4 + h] = ps; adst4[nid * 4 + h] = pd; }
}

// edge-parallel weight precompute: sw1[h][i] = (src, w) with w = exp(leaky(asrc+adst)).
// Unnormalized exp is exact for alpha = w/z (e is O(+-4): no overflow).
__global__ void edge_w1(const int* __restrict__ srclist, const int* __restrict__ dst_sorted,
                        const float4* __restrict__ asrc4, const float4* __restrict__ adst4,
                        int2* __restrict__ sw1) {
    int i = blockIdx.x * blockDim.x + threadIdx.x;
    if (i >= NPAD) return;
    if (i < NTOT) {
        int s = srclist[i], d = dst_sorted[i];
        float4 as = asrc4[s], ad = adst4[d];
        float e0 = as.x + ad.x, e1 = as.y + ad.y, e2 = as.z + ad.z, e3 = as.w + ad.w;
        e0 = fmaxf(e0, NEG_SLOPE * e0); e1 = fmaxf(e1, NEG_SLOPE * e1);
        e2 = fmaxf(e2, NEG_SLOPE * e2); e3 = fmaxf(e3, NEG_SLOPE * e3);
        sw1[0 * NPAD + i] = make_int2(s, __float_as_int(__expf(e0)));
        sw1[1 * NPAD + i] = make_int2(s, __float_as_int(__expf(e1)));
        sw1[2 * NPAD + i] = make_int2(s, __float_as_int(__expf(e2)));
        sw1[3 * NPAD + i] = make_int2(s, __float_as_int(__expf(e3)));
    } else {  // pad: safe (s=0, w=0)
        sw1[0 * NPAD + i] = make_int2(0, 0);
        sw1[1 * NPAD + i] = make_int2(0, 0);
        sw1[2 * NPAD + i] = make_int2(0, 0);
        sw1[3 * NPAD + i] = make_int2(0, 0);
    }
}

// 8 waves/block, one (node, shard) per wave; shard = blockIdx&7 -> XCD via round-robin.
// Lane layout: q = lane>>3 (8 edge slots), r = lane&7 (4 dims via one 8B load).
// No exp, no shuffles in the hot loop; z accumulated for free and reduced with the dims.
__global__ void layer1_aggr(const __half* __restrict__ h1s, const int* __restrict__ rowstart,
                            const int2* __restrict__ sw1, const float* __restrict__ b1,
                            __half* __restrict__ out1) {
    int g = blockIdx.x;
    int shard = g & 7, h = shard >> 1, half = shard & 1;
    int wid = threadIdx.x >> 6, lane = threadIdx.x & 63;
    int nid = (g >> 3) * 8 + wid;
    int q = lane >> 3, r = lane & 7;
    int beg = rowstart[nid], end = rowstart[nid + 1];
    const int2* sw = sw1 + (size_t)h * NPAD;
    const char* hbase = (const char*)h1s + (size_t)shard * NNODES * 64 + r * 8;

    float ax = 0.f, ay = 0.f, az = 0.f, aw = 0.f, zs = 0.f;
    for (int i0 = beg; i0 < end; i0 += 8) {
        int i = i0 + q;
        int2 rec = sw[i];                         // 8 lanes/slot share the address
        float w = (i < end) ? __int_as_float(rec.y) : 0.f;
        zs += w;
        float2 hv = *(const float2*)(hbase + ((size_t)rec.x << 6));  // 8B = 4 dims
        __half2 p0 = *(__half2*)&hv.x, p1 = *(__half2*)&hv.y;
        float2 v0 = __half22float2(p0), v1 = __half22float2(p1);
        ax += w * v0.x; ay += w * v0.y; az += w * v1.x; aw += w * v1.y;
    }
#pragma unroll
    for (int off = 8; off < 64; off <<= 1) {  // reduce over the 8 edge slots (lane bits 3..5)
        ax += __shfl_xor(ax, off, 64);
        ay += __shfl_xor(ay, off, 64);
        az += __shfl_xor(az, off, 64);
        aw += __shfl_xor(aw, off, 64);
        zs += __shfl_xor(zs, off, 64);
    }
    if (q == 0) {
        float rz = 1.f / zs;
        float4 bo = ((const float4*)b1)[h * 16 + half * 8 + r];
        float o0 = ax * rz + bo.x, o1 = ay * rz + bo.y;
        float o2 = az * rz + bo.z, o3 = aw * rz + bo.w;
        o0 = o0 > 0.f ? o0 : __expf(o0) - 1.f;  // ELU
        o1 = o1 > 0.f ? o1 : __expf(o1) - 1.f;
        o2 = o2 > 0.f ? o2 : __expf(o2) - 1.f;
        o3 = o3 > 0.f ? o3 : __expf(o3) - 1.f;
        __half2 r0 = __floats2half2_rn(o0, o1), r1 = __floats2half2_rn(o2, o3);
        float2 st;
        *(__half2*)&st.x = r0; *(__half2*)&st.y = r1;
        *(float2*)(out1 + nid * 256 + h * 64 + half * 32 + r * 4) = st;  // 8B store
    }
}

// ---------------- layer 2 ----------------

// 4 waves/block, one node per wave: h2 = elu_out @ W2 (256->64, fp16 weights),
// h2 stored in 2 shards; attention dots (heads=1). Wave-private LDS row, no barrier.
__global__ void layer2_proj(const __half* __restrict__ out1, const __half* __restrict__ W2h,
                            const float* __restrict__ att_src2, const float* __restrict__ att_dst2,
                            __half* __restrict__ h2s, float* __restrict__ as2,
                            float* __restrict__ ad2) {
    int wid = threadIdx.x >> 6, t = threadIdx.x & 63;
    int nid = blockIdx.x * 4 + wid;
    int sub = t >> 5, d = t & 31;
    __shared__ float row[4][256];
    const __half2* r = (const __half2*)(out1 + nid * 256);
    for (int k = t; k < 128; k += 64) {
        float2 v = __half22float2(r[k]);
        row[wid][2 * k] = v.x; row[wid][2 * k + 1] = v.y;
    }
    // wave-coherent LDS: no __syncthreads needed
    float ax = 0.f, ay = 0.f;
    const __half2* wp = (const __half2*)W2h;  // [256][64] halves -> half2 index k*32+d
#pragma unroll 8
    for (int kk = 0; kk < 128; ++kk) {
        int k = sub * 128 + kk;
        float2 wv = __half22float2(wp[k * 32 + d]);
        float rv = row[wid][k];
        ax += rv * wv.x;
        ay += rv * wv.y;
    }
    ax += __shfl_xor(ax, 32, 64);
    ay += __shfl_xor(ay, 32, 64);
    // both halves hold full sums for dims (2d, 2d+1); shard = d>>4 (dims 0..31 / 32..63)
    if (sub == 0)
        ((__half2*)h2s)[((size_t)(d >> 4) * NNODES + nid) * 16 + (d & 15)] = __floats2half2_rn(ax, ay);
    float2 asv = ((const float2*)att_src2)[d];
    float2 adv = ((const float2*)att_dst2)[d];
    float ps = ax * asv.x + ay * asv.y;
    float pd = ax * adv.x + ay * adv.y;
#pragma unroll
    for (int off = 16; off; off >>= 1) {
        ps += __shfl_xor(ps, off, 64);
        pd += __shfl_xor(pd, off, 64);
    }
    if (t == 0) { as2[nid] = ps; ad2[nid] = pd; }
}

__global__ void edge_w2(const int* __restrict__ srclist, const int* __restrict__ dst_sorted,
                        const float* __restrict__ as2, const float* __restrict__ ad2,
                        int2* __restrict__ sw2) {
    int i = blockIdx.x * blockDim.x + threadIdx.x;
    if (i >= NPAD) return;
    if (i < NTOT) {
        int s = srclist[i], d = dst_sorted[i];
        float e = as2[s] + ad2[d];
        e = fmaxf(e, NEG_SLOPE * e);
        sw2[i] = make_int2(s, __float_as_int(__expf(e)));
    } else {
        sw2[i] = make_int2(0, 0);
    }
}

// 8 waves/block, one (node, shard) per wave; shard = blockIdx&1 -> even/odd XCDs.
__global__ void layer2_aggr(const __half* __restrict__ h2s, const int* __restrict__ rowstart,
                            const int2* __restrict__ sw2, const float* __restrict__ b2,
                            float* __restrict__ out2) {
    int g = blockIdx.x;
    int shard = g & 1;
    int wid = threadIdx.x >> 6, lane = threadIdx.x & 63;
    int nid = (g >> 1) * 8 + wid;
    int q = lane >> 3, r = lane & 7;
    int beg = rowstart[nid], end = rowstart[nid + 1];
    const char* hbase = (const char*)h2s + (size_t)shard * NNODES * 64 + r * 8;

    float ax = 0.f, ay = 0.f, az = 0.f, aw = 0.f, zs = 0.f;
    for (int i0 = beg; i0 < end; i0 += 8) {
        int i = i0 + q;
        int2 rec = sw2[i];
        float w = (i < end) ? __int_as_float(rec.y) : 0.f;
        zs += w;
        float2 hv = *(const float2*)(hbase + ((size_t)rec.x << 6));
        __half2 p0 = *(__half2*)&hv.x, p1 = *(__half2*)&hv.y;
        float2 v0 = __half22float2(p0), v1 = __half22float2(p1);
        ax += w * v0.x; ay += w * v0.y; az += w * v1.x; aw += w * v1.y;
    }
#pragma unroll
    for (int off = 8; off < 64; off <<= 1) {
        ax += __shfl_xor(ax, off, 64);
        ay += __shfl_xor(ay, off, 64);
        az += __shfl_xor(az, off, 64);
        aw += __shfl_xor(aw, off, 64);
        zs += __shfl_xor(zs, off, 64);
    }
    if (q == 0) {
        float rz = 1.f / zs;
        float4 bo = ((const float4*)b2)[shard * 8 + r];
        float4 st = make_float4(ax * rz + bo.x, ay * rz + bo.y,
                                az * rz + bo.z, aw * rz + bo.w);
        *(float4*)(out2 + nid * 64 + shard * 32 + r * 4) = st;
    }
}

// ---------------- final mean over nodes ----------------

__global__ void reduce_kernel(const float* __restrict__ out2, float* __restrict__ dout) {
    int t = threadIdx.x;
    int col = t & 63, sub = t >> 6;
    float acc = 0.f;
    for (int r = blockIdx.x * 4 + sub; r < NNODES; r += 256 * 4)
        acc += out2[r * 64 + col];
    __shared__ float sh[256];
    sh[t] = acc;
    __syncthreads();
    if (t < 64) {
        float v = sh[t] + sh[t + 64] + sh[t + 128] + sh[t + 192];
        atomicAdd(&dout[t], v * (1.0f / NNODES));
    }
}

// ---------------- launch ----------------

extern "C" void kernel_launch(void* const* d_in, const int* in_sizes, int n_in,
                              void* d_out, int out_size, void* d_ws, size_t ws_size,
                              hipStream_t stream) {
    const float* x        = (const float*)d_in[0];
    const int*   ei       = (const int*)d_in[1];   // [2, E] -> src row then dst row
    const float* W1       = (const float*)d_in[2];
    const float* att_src1 = (const float*)d_in[3];
    const float* att_dst1 = (const float*)d_in[4];
    const float* b1       = (const float*)d_in[5];
    const float* W2       = (const float*)d_in[6];
    const float* att_src2 = (const float*)d_in[7];
    const float* att_dst2 = (const float*)d_in[8];
    const float* b2       = (const float*)d_in[9];
    float* out = (float*)d_out;

    char* ws = (char*)d_ws;
    size_t off = 0;
    auto take = [&](size_t bytes) -> char* {
        char* p = ws + off;
        off = (off + bytes + 255) & ~(size_t)255;
        return p;
    };
    int*    deg        = (int*)take(NNODES * sizeof(int));
    int*    rowstart   = (int*)take((NNODES + 1) * sizeof(int));
    int*    cursor     = (int*)take(NNODES * sizeof(int));
    int*    partials   = (int*)take(256 * sizeof(int));
    int*    blockoff   = (int*)take(256 * sizeof(int));
    int*    srclist    = (int*)take((size_t)NTOT * sizeof(int));
    int*    dst_sorted = (int*)take((size_t)NTOT * sizeof(int));
    float*  asrc4      = (float*)take((size_t)NNODES * 4 * sizeof(float));
    float*  adst4      = (float*)take((size_t)NNODES * 4 * sizeof(float));
    __half* h1s        = (__half*)take((size_t)NNODES * 256 * sizeof(__half));
    __half* out1       = (__half*)take((size_t)NNODES * 256 * sizeof(__half));
    int2*   sw1        = (int2*)take((size_t)4 * NPAD * sizeof(int2));
    __half* W2h        = (__half*)take(256 * 64 * sizeof(__half));
    float*  out2       = (float*)take((size_t)NNODES * 64 * sizeof(float));
    // aliases: h1s dead after layer1_aggr; sw1 dead after layer1_aggr; asrc4/adst4 dead too
    __half* h2s = h1s;
    int2*   sw2 = sw1;
    float*  as2 = asrc4;
    float*  ad2 = adst4;

    const int* srcs = ei;
    const int* dsts = ei + NEDGES;
    const int NB = (NNODES + 255) / 256;  // 196

    prep_init<<<NB, 256, 0, stream>>>(deg, cursor);
    hist_kernel<<<(NEDGES + 255) / 256, 256, 0, stream>>>(dsts, deg);
    scanA<<<NB, 256, 0, stream>>>(deg, rowstart, partials);
    scanB<<<1, 256, 0, stream>>>(partials, blockoff, rowstart, NB);
    scanC<<<NB, 256, 0, stream>>>(rowstart, blockoff);
    scatter_kernel<<<(NTOT + 255) / 256, 256, 0, stream>>>(srcs, dsts, rowstart, cursor,
                                                           srclist, dst_sorted);
    w2_convert<<<64, 256, 0, stream>>>(W2, W2h);

    layer1_proj<<<NNODES, 256, 0, stream>>>(x, W1, att_src1, att_dst1, h1s, asrc4, adst4);
    edge_w1<<<(NPAD + 255) / 256, 256, 0, stream>>>(srclist, dst_sorted,
                                                    (const float4*)asrc4, (const float4*)adst4, sw1);
    layer1_aggr<<<(NNODES / 8) * 8, 512, 0, stream>>>(h1s, rowstart, sw1, b1, out1);

    layer2_proj<<<NNODES / 4, 256, 0, stream>>>(out1, W2h, att_src2, att_dst2, h2s, as2, ad2);
    edge_w2<<<(NPAD + 255) / 256, 256, 0, stream>>>(srclist, dst_sorted, as2, ad2, sw2);
    layer2_aggr<<<(NNODES / 8) * 2, 512, 0, stream>>>(h2s, rowstart, sw2, b2, out2);

    hipMemsetAsync(d_out, 0, 64 * sizeof(float), stream);
    reduce_kernel<<<256, 256, 0, stream>>>(out2, out);
}

// Round 5
// 346.273 us; speedup vs baseline: 1.4385x; 1.4385x over previous
//
#include <hip/hip_runtime.h>
#include <hip/hip_fp16.h>

#define NNODES 50000
#define NEDGES 800000
#define NEG_SLOPE 0.2f
#define NTOT (NEDGES + NNODES)

typedef _Float16 half8 __attribute__((ext_vector_type(8)));
typedef float f32x4 __attribute__((ext_vector_type(4)));

// ---------------- graph prep ----------------

__global__ void prep_init(int* deg, int* cursor) {
    int i = blockIdx.x * blockDim.x + threadIdx.x;
    if (i < NNODES) { deg[i] = 1; cursor[i] = 0; }  // deg starts at 1: self-loop
}

__global__ void hist_kernel(const int* __restrict__ dsts, int* __restrict__ deg) {
    int e = blockIdx.x * blockDim.x + threadIdx.x;
    if (e < NEDGES) atomicAdd(&deg[dsts[e]], 1);
}

// hierarchical exclusive scan: A (per-block), B (block totals), C (add offsets)
__global__ void scanA(const int* __restrict__ deg, int* __restrict__ rowstart,
                      int* __restrict__ partials) {
    int b = blockIdx.x, t = threadIdx.x, lane = t & 63, wid = t >> 6;
    int i = b * 256 + t;
    int v = (i < NNODES) ? deg[i] : 0;
    int incl = v;
#pragma unroll
    for (int off = 1; off < 64; off <<= 1) {
        int u = __shfl_up(incl, off, 64);
        if (lane >= off) incl += u;
    }
    __shared__ int ws[4];
    if (lane == 63) ws[wid] = incl;
    __syncthreads();
    int w0 = ws[0], w1 = ws[1], w2 = ws[2], w3 = ws[3];
    int woff = (wid > 0 ? w0 : 0) + (wid > 1 ? w1 : 0) + (wid > 2 ? w2 : 0);
    if (i < NNODES) rowstart[i] = woff + (incl - v);
    if (t == 0) partials[b] = w0 + w1 + w2 + w3;
}

__global__ void scanB(const int* __restrict__ partials, int* __restrict__ blockoff,
                      int* __restrict__ rowstart, int nb) {
    int t = threadIdx.x, lane = t & 63, wid = t >> 6;
    int v = (t < nb) ? partials[t] : 0;
    int incl = v;
#pragma unroll
    for (int off = 1; off < 64; off <<= 1) {
        int u = __shfl_up(incl, off, 64);
        if (lane >= off) incl += u;
    }
    __shared__ int ws[4];
    if (lane == 63) ws[wid] = incl;
    __syncthreads();
    int w0 = ws[0], w1 = ws[1], w2 = ws[2];
    int woff = (wid > 0 ? w0 : 0) + (wid > 1 ? w1 : 0) + (wid > 2 ? w2 : 0);
    if (t < nb) blockoff[t] = woff + (incl - v);
    if (t == 0) rowstart[NNODES] = NTOT;
}

__global__ void scanC(int* __restrict__ rowstart, const int* __restrict__ blockoff) {
    int b = blockIdx.x, t = threadIdx.x;
    int i = b * 256 + t;
    if (i < NNODES) rowstart[i] += blockoff[b];
}

__global__ void scatter_kernel(const int* __restrict__ srcs, const int* __restrict__ dsts,
                               const int* __restrict__ rowstart, int* __restrict__ cursor,
                               int* __restrict__ srclist) {
    int e = blockIdx.x * blockDim.x + threadIdx.x;
    if (e < NEDGES) {
        int s = srcs[e], d = dsts[e];
        int pos = atomicAdd(&cursor[d], 1);
        srclist[rowstart[d] + pos] = s;
    } else if (e < NTOT) {
        int d = e - NEDGES;
        int pos = atomicAdd(&cursor[d], 1);
        srclist[rowstart[d] + pos] = d;  // self-loop
    }
}

// W2 [256][64] f32 -> W2T [64][256] f16 (B-operand friendly: contiguous K)
__global__ void w2t_convert(const float* __restrict__ W2, _Float16* __restrict__ W2T) {
    int idx = blockIdx.x * blockDim.x + threadIdx.x;  // 16384
    int n = idx >> 8, k = idx & 255;
    W2T[n * 256 + k] = (_Float16)W2[k * 64 + n];
}

// ---------------- layer 1 ----------------

// one wave per node: h1 = x @ W1 (fp16 [node][256] rows), att dots per head.
// lane owns output dims 4c..4c+3 (all within head c>>4).
__global__ void layer1_proj(const float* __restrict__ x, const float* __restrict__ W1,
                            const float* __restrict__ att_src, const float* __restrict__ att_dst,
                            __half* __restrict__ h1, float* __restrict__ asrc4,
                            float* __restrict__ adst4) {
    int wid = threadIdx.x >> 6, c = threadIdx.x & 63;
    int nid = __builtin_amdgcn_readfirstlane(blockIdx.x * 4 + wid);
    float a0 = 0.f, a1 = 0.f, a2 = 0.f, a3 = 0.f;
#pragma unroll
    for (int k = 0; k < 15; ++k) {
        float xk = x[nid * 15 + k];                       // scalar (uniform) load
        float4 wv = *(const float4*)(W1 + k * 256 + c * 4);
        a0 += xk * wv.x; a1 += xk * wv.y; a2 += xk * wv.z; a3 += xk * wv.w;
    }
    __half2 r0 = __floats2half2_rn(a0, a1), r1 = __floats2half2_rn(a2, a3);
    float2 st; *(__half2*)&st.x = r0; *(__half2*)&st.y = r1;
    *(float2*)(h1 + (size_t)nid * 256 + c * 4) = st;
    float4 as = *(const float4*)(att_src + c * 4);
    float4 ad = *(const float4*)(att_dst + c * 4);
    float ps = a0 * as.x + a1 * as.y + a2 * as.z + a3 * as.w;
    float pd = a0 * ad.x + a1 * ad.y + a2 * ad.z + a3 * ad.w;
#pragma unroll
    for (int off = 1; off < 16; off <<= 1) {   // reduce within 16-lane head group
        ps += __shfl_xor(ps, off, 64);
        pd += __shfl_xor(pd, off, 64);
    }
    if ((c & 15) == 0) {
        asrc4[nid * 4 + (c >> 4)] = ps;
        adst4[nid * 4 + (c >> 4)] = pd;
    }
}

// one wave per node, ALL heads/dims. Per edge: scalar srclist load, per-lane-head
// weight (exp fused), contiguous 512 B row gather. z redundant per lane -> NO reduction.
__global__ void layer1_aggr(const __half* __restrict__ h1, const int* __restrict__ rowstart,
                            const int* __restrict__ srclist,
                            const float* __restrict__ asrc4, const float* __restrict__ adst4,
                            const float* __restrict__ b1, __half* __restrict__ out1) {
    int wid = threadIdx.x >> 6, lane = threadIdx.x & 63;
    int nid = blockIdx.x * 4 + wid;
    int h = lane >> 4;
    int beg = __builtin_amdgcn_readfirstlane(rowstart[nid]);
    int end = __builtin_amdgcn_readfirstlane(rowstart[nid + 1]);
    float ad = adst4[nid * 4 + h];
    float ax = 0.f, ay = 0.f, az = 0.f, aw = 0.f, zs = 0.f;
    for (int i = beg; i < end; ++i) {
        int s = srclist[i];                               // s_load: i is SGPR-uniform
        float e = asrc4[s * 4 + h] + ad;                  // 1 line (16 B span)
        e = fmaxf(e, NEG_SLOPE * e);
        float w = __expf(e);                              // unnormalized softmax: exact for w/z
        zs += w;
        float2 hv = *(const float2*)(h1 + (size_t)s * 256 + lane * 4);  // 512 B/wave
        __half2 p0 = *(__half2*)&hv.x, p1 = *(__half2*)&hv.y;
        float2 v0 = __half22float2(p0), v1 = __half22float2(p1);
        ax += w * v0.x; ay += w * v0.y; az += w * v1.x; aw += w * v1.y;
    }
    float rz = 1.f / zs;
    float4 bo = ((const float4*)b1)[lane];
    float o0 = ax * rz + bo.x, o1 = ay * rz + bo.y;
    float o2 = az * rz + bo.z, o3 = aw * rz + bo.w;
    o0 = o0 > 0.f ? o0 : __expf(o0) - 1.f;  // ELU
    o1 = o1 > 0.f ? o1 : __expf(o1) - 1.f;
    o2 = o2 > 0.f ? o2 : __expf(o2) - 1.f;
    o3 = o3 > 0.f ? o3 : __expf(o3) - 1.f;
    __half2 r0 = __floats2half2_rn(o0, o1), r1 = __floats2half2_rn(o2, o3);
    float2 st; *(__half2*)&st.x = r0; *(__half2*)&st.y = r1;
    *(float2*)(out1 + (size_t)nid * 256 + lane * 4) = st;
}

// ---------------- layer 2 ----------------

// MFMA GEMM: h2[50000x64] = out1[50000x256] @ W2 (f16 in, f32 acc, f16 out).
// A-frag: A[m=lane&15][k=quad*8+j]; B-frag: B[k=quad*8+j][n=lane&15] from W2T;
// C/D: row=quad*4+reg, col=lane&15.
__global__ __launch_bounds__(256) void layer2_gemm(const __half* __restrict__ out1,
                                                   const _Float16* __restrict__ W2T,
                                                   __half* __restrict__ h2) {
    int w = threadIdx.x >> 6, lane = threadIdx.x & 63;
    int m16 = lane & 15, quad = lane >> 4;
    int r0 = blockIdx.x * 64 + w * 16;
    const _Float16* A = (const _Float16*)out1;
    f32x4 acc[4] = {{0.f,0.f,0.f,0.f},{0.f,0.f,0.f,0.f},{0.f,0.f,0.f,0.f},{0.f,0.f,0.f,0.f}};
    int row = r0 + m16; if (row >= NNODES) row = NNODES - 1;   // clamp tail reads
#pragma unroll
    for (int k0 = 0; k0 < 256; k0 += 32) {
        half8 a = *(const half8*)(A + (size_t)row * 256 + k0 + quad * 8);
#pragma unroll
        for (int nt = 0; nt < 4; ++nt) {
            half8 b = *(const half8*)(W2T + (size_t)(nt * 16 + m16) * 256 + k0 + quad * 8);
            acc[nt] = __builtin_amdgcn_mfma_f32_16x16x32_f16(a, b, acc[nt], 0, 0, 0);
        }
    }
    __shared__ _Float16 tile[64][72];  // pad 8 halves: 16B-aligned rows + bank stagger
#pragma unroll
    for (int nt = 0; nt < 4; ++nt)
#pragma unroll
        for (int r = 0; r < 4; ++r)
            tile[w * 16 + quad * 4 + r][nt * 16 + m16] = (_Float16)acc[nt][r];
    __syncthreads();
    int t = threadIdx.x;
    int trow = t >> 2, seg = t & 3;
    int rg = blockIdx.x * 64 + trow;
    if (rg < NNODES) {
        float4 v0 = *(float4*)&tile[trow][seg * 16];
        float4 v1 = *(float4*)&tile[trow][seg * 16 + 8];
        _Float16* dst = (_Float16*)h2 + (size_t)rg * 64 + seg * 16;
        *(float4*)dst = v0;
        *(float4*)(dst + 8) = v1;
    }
}

// one wave per node: attention dots on h2 (heads=1)
__global__ void attdot2(const __half* __restrict__ h2, const float* __restrict__ att_src2,
                        const float* __restrict__ att_dst2, float* __restrict__ as2,
                        float* __restrict__ ad2) {
    int wid = threadIdx.x >> 6, lane = threadIdx.x & 63;
    int nid = blockIdx.x * 4 + wid;
    float hv = __half2float(h2[(size_t)nid * 64 + lane]);
    float ps = hv * att_src2[lane];
    float pd = hv * att_dst2[lane];
#pragma unroll
    for (int off = 1; off < 64; off <<= 1) {
        ps += __shfl_xor(ps, off, 64);
        pd += __shfl_xor(pd, off, 64);
    }
    if (lane == 0) { as2[nid] = ps; ad2[nid] = pd; }
}

// one wave per node; 16-lane groups process 4 edges/iter; exp fused; 2 xor-reduces.
__global__ void layer2_aggr(const __half* __restrict__ h2, const int* __restrict__ rowstart,
                            const int* __restrict__ srclist,
                            const float* __restrict__ as2, const float* __restrict__ ad2,
                            const float* __restrict__ b2, float* __restrict__ out2) {
    int wid = threadIdx.x >> 6, lane = threadIdx.x & 63;
    int nid = blockIdx.x * 4 + wid;
    int q = lane >> 4, c = lane & 15;
    int beg = __builtin_amdgcn_readfirstlane(rowstart[nid]);
    int end = __builtin_amdgcn_readfirstlane(rowstart[nid + 1]);
    float ad = ad2[nid];
    float ax = 0.f, ay = 0.f, az = 0.f, aw = 0.f, zs = 0.f;
    for (int i0 = beg; i0 < end; i0 += 4) {
        int i = i0 + q;
        bool valid = i < end;
        int s = valid ? srclist[i] : 0;       // srclist padded; masked s keeps gather in-bounds
        float e = as2[s] + ad;
        e = fmaxf(e, NEG_SLOPE * e);
        float w = valid ? __expf(e) : 0.f;
        zs += w;
        float2 hv = *(const float2*)(h2 + (size_t)s * 64 + c * 4);  // 128 B/edge
        __half2 p0 = *(__half2*)&hv.x, p1 = *(__half2*)&hv.y;
        float2 v0 = __half22float2(p0), v1 = __half22float2(p1);
        ax += w * v0.x; ay += w * v0.y; az += w * v1.x; aw += w * v1.y;
    }
#pragma unroll
    for (int off = 16; off < 64; off <<= 1) {  // reduce across 4 edge groups
        ax += __shfl_xor(ax, off, 64);
        ay += __shfl_xor(ay, off, 64);
        az += __shfl_xor(az, off, 64);
        aw += __shfl_xor(aw, off, 64);
        zs += __shfl_xor(zs, off, 64);
    }
    if (lane < 16) {
        float rz = 1.f / zs;
        float4 bo = ((const float4*)b2)[c];
        float4 st = make_float4(ax * rz + bo.x, ay * rz + bo.y,
                                az * rz + bo.z, aw * rz + bo.w);
        *(float4*)(out2 + (size_t)nid * 64 + c * 4) = st;
    }
}

// ---------------- final mean over nodes ----------------

__global__ void reduce_kernel(const float* __restrict__ out2, float* __restrict__ dout) {
    int t = threadIdx.x;
    int col = t & 63, sub = t >> 6;
    float acc = 0.f;
    for (int r = blockIdx.x * 4 + sub; r < NNODES; r += 256 * 4)
        acc += out2[r * 64 + col];
    __shared__ float sh[256];
    sh[t] = acc;
    __syncthreads();
    if (t < 64) {
        float v = sh[t] + sh[t + 64] + sh[t + 128] + sh[t + 192];
        atomicAdd(&dout[t], v * (1.0f / NNODES));
    }
}

// ---------------- launch ----------------

extern "C" void kernel_launch(void* const* d_in, const int* in_sizes, int n_in,
                              void* d_out, int out_size, void* d_ws, size_t ws_size,
                              hipStream_t stream) {
    const float* x        = (const float*)d_in[0];
    const int*   ei       = (const int*)d_in[1];   // [2, E] -> src row then dst row
    const float* W1       = (const float*)d_in[2];
    const float* att_src1 = (const float*)d_in[3];
    const float* att_dst1 = (const float*)d_in[4];
    const float* b1       = (const float*)d_in[5];
    const float* W2       = (const float*)d_in[6];
    const float* att_src2 = (const float*)d_in[7];
    const float* att_dst2 = (const float*)d_in[8];
    const float* b2       = (const float*)d_in[9];
    float* out = (float*)d_out;

    char* ws = (char*)d_ws;
    size_t off = 0;
    auto take = [&](size_t bytes) -> char* {
        char* p = ws + off;
        off = (off + bytes + 255) & ~(size_t)255;
        return p;
    };
    int*      deg      = (int*)take(NNODES * sizeof(int));
    int*      rowstart = (int*)take((NNODES + 1) * sizeof(int));
    int*      cursor   = (int*)take(NNODES * sizeof(int));
    int*      partials = (int*)take(256 * sizeof(int));
    int*      blockoff = (int*)take(256 * sizeof(int));
    int*      srclist  = (int*)take(((size_t)NTOT + 16) * sizeof(int));  // +pad for masked tail
    float*    asrc4    = (float*)take((size_t)NNODES * 4 * sizeof(float));
    float*    adst4    = (float*)take((size_t)NNODES * 4 * sizeof(float));
    __half*   h1       = (__half*)take((size_t)NNODES * 256 * sizeof(__half));
    __half*   out1     = (__half*)take((size_t)NNODES * 256 * sizeof(__half));
    _Float16* W2T      = (_Float16*)take(64 * 256 * sizeof(_Float16));
    __half*   h2       = (__half*)take((size_t)NNODES * 64 * sizeof(__half));
    float*    as2      = (float*)take((size_t)NNODES * sizeof(float));
    float*    ad2      = (float*)take((size_t)NNODES * sizeof(float));
    float*    out2     = (float*)take((size_t)NNODES * 64 * sizeof(float));

    const int* srcs = ei;
    const int* dsts = ei + NEDGES;
    const int NB = (NNODES + 255) / 256;  // 196

    prep_init<<<NB, 256, 0, stream>>>(deg, cursor);
    hist_kernel<<<(NEDGES + 255) / 256, 256, 0, stream>>>(dsts, deg);
    scanA<<<NB, 256, 0, stream>>>(deg, rowstart, partials);
    scanB<<<1, 256, 0, stream>>>(partials, blockoff, rowstart, NB);
    scanC<<<NB, 256, 0, stream>>>(rowstart, blockoff);
    scatter_kernel<<<(NTOT + 255) / 256, 256, 0, stream>>>(srcs, dsts, rowstart, cursor, srclist);
    w2t_convert<<<64, 256, 0, stream>>>(W2, W2T);

    layer1_proj<<<NNODES / 4, 256, 0, stream>>>(x, W1, att_src1, att_dst1, h1, asrc4, adst4);
    layer1_aggr<<<NNODES / 4, 256, 0, stream>>>(h1, rowstart, srclist, asrc4, adst4, b1, out1);

    layer2_gemm<<<(NNODES + 63) / 64, 256, 0, stream>>>(out1, W2T, h2);
    attdot2<<<NNODES / 4, 256, 0, stream>>>(h2, att_src2, att_dst2, as2, ad2);
    layer2_aggr<<<NNODES / 4, 256, 0, stream>>>(h2, rowstart, srclist, as2, ad2, b2, out2);

    hipMemsetAsync(d_out, 0, 64 * sizeof(float), stream);
    reduce_kernel<<<256, 256, 0, stream>>>(out2, out);
}

// Round 6
// 334.015 us; speedup vs baseline: 1.4913x; 1.0367x over previous
//
#include <hip/hip_runtime.h>
#include <hip/hip_fp16.h>

#define NNODES 50000
#define NEDGES 800000
#define NEG_SLOPE 0.2f
#define NTOT (NEDGES + NNODES)

typedef _Float16 half8 __attribute__((ext_vector_type(8)));
typedef float f32x4 __attribute__((ext_vector_type(4)));

// ---------------- graph prep ----------------

// deg=1 (self-loop) + W2 transpose/convert, one launch
__global__ void setup_kernel(int* __restrict__ deg, const float* __restrict__ W2,
                             _Float16* __restrict__ W2T) {
    int i = blockIdx.x * blockDim.x + threadIdx.x;
    if (i < NNODES) {
        deg[i] = 1;
    } else if (i < NNODES + 64 * 256) {
        int idx = i - NNODES;
        int n = idx >> 8, k = idx & 255;
        W2T[n * 256 + k] = (_Float16)W2[k * 64 + n];
    }
}

__global__ void hist_kernel(const int* __restrict__ dsts, int* __restrict__ deg) {
    int e = blockIdx.x * blockDim.x + threadIdx.x;
    if (e < NEDGES) atomicAdd(&deg[dsts[e]], 1);
}

// hierarchical exclusive scan: A (per-block), B (block totals), C (add offsets)
__global__ void scanA(const int* __restrict__ deg, int* __restrict__ rowstart,
                      int* __restrict__ partials) {
    int b = blockIdx.x, t = threadIdx.x, lane = t & 63, wid = t >> 6;
    int i = b * 256 + t;
    int v = (i < NNODES) ? deg[i] : 0;
    int incl = v;
#pragma unroll
    for (int off = 1; off < 64; off <<= 1) {
        int u = __shfl_up(incl, off, 64);
        if (lane >= off) incl += u;
    }
    __shared__ int ws[4];
    if (lane == 63) ws[wid] = incl;
    __syncthreads();
    int w0 = ws[0], w1 = ws[1], w2 = ws[2], w3 = ws[3];
    int woff = (wid > 0 ? w0 : 0) + (wid > 1 ? w1 : 0) + (wid > 2 ? w2 : 0);
    if (i < NNODES) rowstart[i] = woff + (incl - v);
    if (t == 0) partials[b] = w0 + w1 + w2 + w3;
}

__global__ void scanB(const int* __restrict__ partials, int* __restrict__ blockoff,
                      int* __restrict__ rowstart, int nb) {
    int t = threadIdx.x, lane = t & 63, wid = t >> 6;
    int v = (t < nb) ? partials[t] : 0;
    int incl = v;
#pragma unroll
    for (int off = 1; off < 64; off <<= 1) {
        int u = __shfl_up(incl, off, 64);
        if (lane >= off) incl += u;
    }
    __shared__ int ws[4];
    if (lane == 63) ws[wid] = incl;
    __syncthreads();
    int w0 = ws[0], w1 = ws[1], w2 = ws[2];
    int woff = (wid > 0 ? w0 : 0) + (wid > 1 ? w1 : 0) + (wid > 2 ? w2 : 0);
    if (t < nb) blockoff[t] = woff + (incl - v);
    if (t == 0) rowstart[NNODES] = NTOT;
}

// adds block offsets AND initializes cursor = rowstart (absolute scatter positions)
__global__ void scanC(int* __restrict__ rowstart, const int* __restrict__ blockoff,
                      int* __restrict__ cursor) {
    int b = blockIdx.x, t = threadIdx.x;
    int i = b * 256 + t;
    if (i < NNODES) {
        int v = rowstart[i] + blockoff[b];
        rowstart[i] = v;
        cursor[i] = v;
    }
}

__global__ void scatter_kernel(const int* __restrict__ srcs, const int* __restrict__ dsts,
                               int* __restrict__ cursor, int* __restrict__ srclist) {
    int e = blockIdx.x * blockDim.x + threadIdx.x;
    if (e < NEDGES) {
        int s = srcs[e], d = dsts[e];
        srclist[atomicAdd(&cursor[d], 1)] = s;
    } else if (e < NTOT) {
        int d = e - NEDGES;
        srclist[atomicAdd(&cursor[d], 1)] = d;  // self-loop
    }
}

// ---------------- layer 1 ----------------

// one wave per node: h1 = x @ W1 (fp16 [node][256] rows), att dots per head.
__global__ void layer1_proj(const float* __restrict__ x, const float* __restrict__ W1,
                            const float* __restrict__ att_src, const float* __restrict__ att_dst,
                            __half* __restrict__ h1, float* __restrict__ asrc4,
                            float* __restrict__ adst4) {
    int wid = threadIdx.x >> 6, c = threadIdx.x & 63;
    int nid = __builtin_amdgcn_readfirstlane(blockIdx.x * 4 + wid);
    float a0 = 0.f, a1 = 0.f, a2 = 0.f, a3 = 0.f;
#pragma unroll
    for (int k = 0; k < 15; ++k) {
        float xk = x[nid * 15 + k];                       // scalar (uniform) load
        float4 wv = *(const float4*)(W1 + k * 256 + c * 4);
        a0 += xk * wv.x; a1 += xk * wv.y; a2 += xk * wv.z; a3 += xk * wv.w;
    }
    __half2 r0 = __floats2half2_rn(a0, a1), r1 = __floats2half2_rn(a2, a3);
    float2 st; *(__half2*)&st.x = r0; *(__half2*)&st.y = r1;
    *(float2*)(h1 + (size_t)nid * 256 + c * 4) = st;
    float4 as = *(const float4*)(att_src + c * 4);
    float4 ad = *(const float4*)(att_dst + c * 4);
    float ps = a0 * as.x + a1 * as.y + a2 * as.z + a3 * as.w;
    float pd = a0 * ad.x + a1 * ad.y + a2 * ad.z + a3 * ad.w;
#pragma unroll
    for (int off = 1; off < 16; off <<= 1) {   // reduce within 16-lane head group
        ps += __shfl_xor(ps, off, 64);
        pd += __shfl_xor(pd, off, 64);
    }
    if ((c & 15) == 0) {
        asrc4[nid * 4 + (c >> 4)] = ps;
        adst4[nid * 4 + (c >> 4)] = pd;
    }
}

// one wave per node; wave splits into 2 halves, each half owns one edge with
// 16 B/lane (half8). 2 edge-pairs per iteration => 4 gathers in flight.
// z redundant per lane within a half; one xor-32 reduce at the end.
__global__ void layer1_aggr(const __half* __restrict__ h1, const int* __restrict__ rowstart,
                            const int* __restrict__ srclist,
                            const float* __restrict__ asrc4, const float* __restrict__ adst4,
                            const float* __restrict__ b1, __half* __restrict__ out1) {
    int wid = threadIdx.x >> 6, lane = threadIdx.x & 63;
    int nid = blockIdx.x * 4 + wid;
    int hf = lane >> 5, l32 = lane & 31;
    int h = l32 >> 3;                       // head (8 lanes x 8 dims per head)
    int beg = __builtin_amdgcn_readfirstlane(rowstart[nid]);
    int end = __builtin_amdgcn_readfirstlane(rowstart[nid + 1]);
    float ad = adst4[nid * 4 + h];
    const __half* hb = h1 + l32 * 8;        // lane's dim-octet base
    float a0=0.f,a1=0.f,a2=0.f,a3=0.f,a4=0.f,a5=0.f,a6=0.f,a7=0.f,zs=0.f;
    for (int i0 = beg; i0 < end; i0 += 4) {
        int ia = i0 + hf, ib = ia + 2;
        bool va = ia < end, vb = ib < end;
        int sa = va ? srclist[ia] : 0;
        int sb = vb ? srclist[ib] : 0;
        half8 ga = *(const half8*)(hb + (size_t)sa * 256);   // issue both gathers
        half8 gb = *(const half8*)(hb + (size_t)sb * 256);
        float ea = asrc4[sa * 4 + h] + ad;
        float eb = asrc4[sb * 4 + h] + ad;
        ea = fmaxf(ea, NEG_SLOPE * ea);
        eb = fmaxf(eb, NEG_SLOPE * eb);
        float wa = va ? __expf(ea) : 0.f;
        float wb = vb ? __expf(eb) : 0.f;
        zs += wa + wb;
        a0 += wa * (float)ga[0] + wb * (float)gb[0];
        a1 += wa * (float)ga[1] + wb * (float)gb[1];
        a2 += wa * (float)ga[2] + wb * (float)gb[2];
        a3 += wa * (float)ga[3] + wb * (float)gb[3];
        a4 += wa * (float)ga[4] + wb * (float)gb[4];
        a5 += wa * (float)ga[5] + wb * (float)gb[5];
        a6 += wa * (float)ga[6] + wb * (float)gb[6];
        a7 += wa * (float)ga[7] + wb * (float)gb[7];
    }
    a0 += __shfl_xor(a0, 32, 64); a1 += __shfl_xor(a1, 32, 64);
    a2 += __shfl_xor(a2, 32, 64); a3 += __shfl_xor(a3, 32, 64);
    a4 += __shfl_xor(a4, 32, 64); a5 += __shfl_xor(a5, 32, 64);
    a6 += __shfl_xor(a6, 32, 64); a7 += __shfl_xor(a7, 32, 64);
    zs += __shfl_xor(zs, 32, 64);
    if (hf == 0) {
        float rz = 1.f / zs;
        float4 bl = *(const float4*)(b1 + l32 * 8);
        float4 bh = *(const float4*)(b1 + l32 * 8 + 4);
        float o0 = a0*rz+bl.x, o1 = a1*rz+bl.y, o2 = a2*rz+bl.z, o3 = a3*rz+bl.w;
        float o4 = a4*rz+bh.x, o5 = a5*rz+bh.y, o6 = a6*rz+bh.z, o7 = a7*rz+bh.w;
        o0 = o0 > 0.f ? o0 : __expf(o0) - 1.f;  // ELU
        o1 = o1 > 0.f ? o1 : __expf(o1) - 1.f;
        o2 = o2 > 0.f ? o2 : __expf(o2) - 1.f;
        o3 = o3 > 0.f ? o3 : __expf(o3) - 1.f;
        o4 = o4 > 0.f ? o4 : __expf(o4) - 1.f;
        o5 = o5 > 0.f ? o5 : __expf(o5) - 1.f;
        o6 = o6 > 0.f ? o6 : __expf(o6) - 1.f;
        o7 = o7 > 0.f ? o7 : __expf(o7) - 1.f;
        half8 st;
        st[0]=(_Float16)o0; st[1]=(_Float16)o1; st[2]=(_Float16)o2; st[3]=(_Float16)o3;
        st[4]=(_Float16)o4; st[5]=(_Float16)o5; st[6]=(_Float16)o6; st[7]=(_Float16)o7;
        *(half8*)((_Float16*)out1 + (size_t)nid * 256 + l32 * 8) = st;
    }
}

// ---------------- layer 2 ----------------

// MFMA GEMM: h2[50000x64] = out1[50000x256] @ W2 (f16 in, f32 acc, f16 out),
// with fused attention dots (heads=1) in the epilogue.
__global__ __launch_bounds__(256) void layer2_gemm(const __half* __restrict__ out1,
                                                   const _Float16* __restrict__ W2T,
                                                   __half* __restrict__ h2,
                                                   const float* __restrict__ att_src2,
                                                   const float* __restrict__ att_dst2,
                                                   float* __restrict__ as2,
                                                   float* __restrict__ ad2) {
    int w = threadIdx.x >> 6, lane = threadIdx.x & 63;
    int m16 = lane & 15, quad = lane >> 4;
    int r0 = blockIdx.x * 64 + w * 16;
    const _Float16* A = (const _Float16*)out1;
    f32x4 acc[4] = {{0.f,0.f,0.f,0.f},{0.f,0.f,0.f,0.f},{0.f,0.f,0.f,0.f},{0.f,0.f,0.f,0.f}};
    int row = r0 + m16; if (row >= NNODES) row = NNODES - 1;   // clamp tail reads
#pragma unroll
    for (int k0 = 0; k0 < 256; k0 += 32) {
        half8 a = *(const half8*)(A + (size_t)row * 256 + k0 + quad * 8);
#pragma unroll
        for (int nt = 0; nt < 4; ++nt) {
            half8 b = *(const half8*)(W2T + (size_t)(nt * 16 + m16) * 256 + k0 + quad * 8);
            acc[nt] = __builtin_amdgcn_mfma_f32_16x16x32_f16(a, b, acc[nt], 0, 0, 0);
        }
    }
    __shared__ _Float16 tile[64][72];  // pad 8 halves: 16B-aligned rows + bank stagger
#pragma unroll
    for (int nt = 0; nt < 4; ++nt)
#pragma unroll
        for (int r = 0; r < 4; ++r)
            tile[w * 16 + quad * 4 + r][nt * 16 + m16] = (_Float16)acc[nt][r];
    __syncthreads();
    int t = threadIdx.x;
    int trow = t >> 2, seg = t & 3;
    int rg = blockIdx.x * 64 + trow;
    if (rg < NNODES) {
        float4 v0 = *(float4*)&tile[trow][seg * 16];
        float4 v1 = *(float4*)&tile[trow][seg * 16 + 8];
        _Float16* dst = (_Float16*)h2 + (size_t)rg * 64 + seg * 16;
        *(float4*)dst = v0;
        *(float4*)(dst + 8) = v1;
        // fused attention dots: this thread covers dims seg*16..seg*16+15
        const _Float16* hv = &tile[trow][seg * 16];
        float ps = 0.f, pd = 0.f;
#pragma unroll
        for (int j = 0; j < 16; ++j) {
            float v = (float)hv[j];
            ps += v * att_src2[seg * 16 + j];
            pd += v * att_dst2[seg * 16 + j];
        }
        ps += __shfl_xor(ps, 1, 64); ps += __shfl_xor(ps, 2, 64);
        pd += __shfl_xor(pd, 1, 64); pd += __shfl_xor(pd, 2, 64);
        if (seg == 0) { as2[rg] = ps; ad2[rg] = pd; }
    }
}

// one wave per node; 16-lane groups, 2 edges each per iteration (8 in flight).
__global__ void layer2_aggr(const __half* __restrict__ h2, const int* __restrict__ rowstart,
                            const int* __restrict__ srclist,
                            const float* __restrict__ as2, const float* __restrict__ ad2,
                            const float* __restrict__ b2, float* __restrict__ out2) {
    int wid = threadIdx.x >> 6, lane = threadIdx.x & 63;
    int nid = blockIdx.x * 4 + wid;
    int q = lane >> 4, c = lane & 15;
    int beg = __builtin_amdgcn_readfirstlane(rowstart[nid]);
    int end = __builtin_amdgcn_readfirstlane(rowstart[nid + 1]);
    float ad = ad2[nid];
    float ax = 0.f, ay = 0.f, az = 0.f, aw = 0.f, zs = 0.f;
    for (int i0 = beg; i0 < end; i0 += 8) {
        int ia = i0 + q, ib = ia + 4;
        bool va = ia < end, vb = ib < end;
        int sa = va ? srclist[ia] : 0;
        int sb = vb ? srclist[ib] : 0;
        float2 hva = *(const float2*)(h2 + (size_t)sa * 64 + c * 4);
        float2 hvb = *(const float2*)(h2 + (size_t)sb * 64 + c * 4);
        float ea = as2[sa] + ad, eb = as2[sb] + ad;
        ea = fmaxf(ea, NEG_SLOPE * ea);
        eb = fmaxf(eb, NEG_SLOPE * eb);
        float wa = va ? __expf(ea) : 0.f;
        float wb = vb ? __expf(eb) : 0.f;
        zs += wa + wb;
        __half2 pa0 = *(__half2*)&hva.x, pa1 = *(__half2*)&hva.y;
        __half2 pb0 = *(__half2*)&hvb.x, pb1 = *(__half2*)&hvb.y;
        float2 va0 = __half22float2(pa0), va1 = __half22float2(pa1);
        float2 vb0 = __half22float2(pb0), vb1 = __half22float2(pb1);
        ax += wa * va0.x + wb * vb0.x;
        ay += wa * va0.y + wb * vb0.y;
        az += wa * va1.x + wb * vb1.x;
        aw += wa * va1.y + wb * vb1.y;
    }
#pragma unroll
    for (int off = 16; off < 64; off <<= 1) {  // reduce across 4 edge groups
        ax += __shfl_xor(ax, off, 64);
        ay += __shfl_xor(ay, off, 64);
        az += __shfl_xor(az, off, 64);
        aw += __shfl_xor(aw, off, 64);
        zs += __shfl_xor(zs, off, 64);
    }
    if (lane < 16) {
        float rz = 1.f / zs;
        float4 bo = ((const float4*)b2)[c];
        float4 st = make_float4(ax * rz + bo.x, ay * rz + bo.y,
                                az * rz + bo.z, aw * rz + bo.w);
        *(float4*)(out2 + (size_t)nid * 64 + c * 4) = st;
    }
}

// ---------------- final mean over nodes ----------------

__global__ void reduce_kernel(const float* __restrict__ out2, float* __restrict__ dout) {
    int t = threadIdx.x;
    int col = t & 63, sub = t >> 6;
    float acc = 0.f;
    for (int r = blockIdx.x * 4 + sub; r < NNODES; r += 256 * 4)
        acc += out2[r * 64 + col];
    __shared__ float sh[256];
    sh[t] = acc;
    __syncthreads();
    if (t < 64) {
        float v = sh[t] + sh[t + 64] + sh[t + 128] + sh[t + 192];
        atomicAdd(&dout[t], v * (1.0f / NNODES));
    }
}

// ---------------- launch ----------------

extern "C" void kernel_launch(void* const* d_in, const int* in_sizes, int n_in,
                              void* d_out, int out_size, void* d_ws, size_t ws_size,
                              hipStream_t stream) {
    const float* x        = (const float*)d_in[0];
    const int*   ei       = (const int*)d_in[1];   // [2, E] -> src row then dst row
    const float* W1       = (const float*)d_in[2];
    const float* att_src1 = (const float*)d_in[3];
    const float* att_dst1 = (const float*)d_in[4];
    const float* b1       = (const float*)d_in[5];
    const float* W2       = (const float*)d_in[6];
    const float* att_src2 = (const float*)d_in[7];
    const float* att_dst2 = (const float*)d_in[8];
    const float* b2       = (const float*)d_in[9];
    float* out = (float*)d_out;

    char* ws = (char*)d_ws;
    size_t off = 0;
    auto take = [&](size_t bytes) -> char* {
        char* p = ws + off;
        off = (off + bytes + 255) & ~(size_t)255;
        return p;
    };
    int*      deg      = (int*)take(NNODES * sizeof(int));
    int*      rowstart = (int*)take((NNODES + 1) * sizeof(int));
    int*      cursor   = (int*)take(NNODES * sizeof(int));
    int*      partials = (int*)take(256 * sizeof(int));
    int*      blockoff = (int*)take(256 * sizeof(int));
    int*      srclist  = (int*)take(((size_t)NTOT + 16) * sizeof(int));  // +pad for masked tail
    float*    asrc4    = (float*)take((size_t)NNODES * 4 * sizeof(float));
    float*    adst4    = (float*)take((size_t)NNODES * 4 * sizeof(float));
    __half*   h1       = (__half*)take((size_t)NNODES * 256 * sizeof(__half));
    __half*   out1     = (__half*)take((size_t)NNODES * 256 * sizeof(__half));
    _Float16* W2T      = (_Float16*)take(64 * 256 * sizeof(_Float16));
    __half*   h2       = (__half*)take((size_t)NNODES * 64 * sizeof(__half));
    float*    as2      = (float*)take((size_t)NNODES * sizeof(float));
    float*    ad2      = (float*)take((size_t)NNODES * sizeof(float));
    float*    out2     = (float*)take((size_t)NNODES * 64 * sizeof(float));

    const int* srcs = ei;
    const int* dsts = ei + NEDGES;
    const int NB = (NNODES + 255) / 256;  // 196

    setup_kernel<<<(NNODES + 64 * 256 + 255) / 256, 256, 0, stream>>>(deg, W2, W2T);
    hist_kernel<<<(NEDGES + 255) / 256, 256, 0, stream>>>(dsts, deg);
    scanA<<<NB, 256, 0, stream>>>(deg, rowstart, partials);
    scanB<<<1, 256, 0, stream>>>(partials, blockoff, rowstart, NB);
    scanC<<<NB, 256, 0, stream>>>(rowstart, blockoff, cursor);
    scatter_kernel<<<(NTOT + 255) / 256, 256, 0, stream>>>(srcs, dsts, cursor, srclist);

    layer1_proj<<<NNODES / 4, 256, 0, stream>>>(x, W1, att_src1, att_dst1, h1, asrc4, adst4);
    layer1_aggr<<<NNODES / 4, 256, 0, stream>>>(h1, rowstart, srclist, asrc4, adst4, b1, out1);

    layer2_gemm<<<(NNODES + 63) / 64, 256, 0, stream>>>(out1, W2T, h2, att_src2, att_dst2,
                                                        as2, ad2);
    layer2_aggr<<<NNODES / 4, 256, 0, stream>>>(h2, rowstart, srclist, as2, ad2, b2, out2);

    hipMemsetAsync(d_out, 0, 64 * sizeof(float), stream);
    reduce_kernel<<<256, 256, 0, stream>>>(out2, out);
}